// Round 2
// baseline (562.022 us; speedup 1.0000x reference)
//
#include <hip/hip_runtime.h>
#include <hip/hip_bf16.h>
#include <stdint.h>

#define H       2048
#define LOGH    11
#define T_TOK   4096
#define NEXP    8
#define NATOM   64
#define NS      16384

typedef short bf16x8 __attribute__((ext_vector_type(8)));
typedef float f32x4  __attribute__((ext_vector_type(4)));

// ---------------- convert x and W to bf16 (RNE) ----------------
__global__ __launch_bounds__(256) void cvt_kernel(
    const float* __restrict__ x, const float* __restrict__ W,
    unsigned short* __restrict__ xb, unsigned short* __restrict__ wb) {
  const int TH = T_TOK * H;
  const int WH = H * H;
  const int total4 = (TH + WH) / 4;
  for (int i = blockIdx.x * blockDim.x + threadIdx.x; i < total4;
       i += gridDim.x * blockDim.x) {
    int e0 = i * 4;
    const float* src;
    unsigned short* dst;
    if (e0 < TH) { src = x + e0; dst = xb + e0; }
    else         { src = W + (e0 - TH); dst = wb + (e0 - TH); }
    float4 v = *reinterpret_cast<const float4*>(src);
    ushort4 o;
    {
      union { float f; unsigned u; } c;
      c.f = v.x; c.u += 0x7fff + ((c.u >> 16) & 1); o.x = (unsigned short)(c.u >> 16);
      c.f = v.y; c.u += 0x7fff + ((c.u >> 16) & 1); o.y = (unsigned short)(c.u >> 16);
      c.f = v.z; c.u += 0x7fff + ((c.u >> 16) & 1); o.z = (unsigned short)(c.u >> 16);
      c.f = v.w; c.u += 0x7fff + ((c.u >> 16) & 1); o.w = (unsigned short)(c.u >> 16);
    }
    *reinterpret_cast<ushort4*>(dst) = o;
  }
}

// ---------------- weighted[e][s] = (softmax(eaw[e]) @ atoms)[s] * sigmoid(imp[e][s]) ----------------
__global__ __launch_bounds__(256) void weighted_kernel(
    const float* __restrict__ eaw, const float* __restrict__ atoms,
    const float* __restrict__ importance, float* __restrict__ weighted) {
  __shared__ float p[NATOM];
  const int e = blockIdx.x >> 3;
  const int chunk = blockIdx.x & 7;
  const int tid = threadIdx.x;
  if (tid < NATOM) p[tid] = eaw[e * NATOM + tid];
  __syncthreads();
  if (tid == 0) {
    float m = p[0];
    for (int a = 1; a < NATOM; ++a) m = fmaxf(m, p[a]);
    float s = 0.f;
    for (int a = 0; a < NATOM; ++a) { p[a] = expf(p[a] - m); s += p[a]; }
    float inv = 1.f / s;
    for (int a = 0; a < NATOM; ++a) p[a] *= inv;
  }
  __syncthreads();
  const int base = chunk * 2048 + tid;
  for (int it = 0; it < 8; ++it) {
    int s = base + it * 256;
    float acc = 0.f;
#pragma unroll 16
    for (int a = 0; a < NATOM; ++a) acc = fmaf(p[a], atoms[a * NS + s], acc);
    float imp = importance[e * NS + s];
    float sig = 1.f / (1.f + expf(-imp));
    weighted[e * NS + s] = acc * sig;
  }
}

// ---------------- bf16 MFMA GEMM: out[m][n] = sum_k xb[m][k] * wb[n][k] ----------------
__global__ __launch_bounds__(256) void gemm_kernel(
    const unsigned short* __restrict__ xb, const unsigned short* __restrict__ wb,
    float* __restrict__ out) {
  __shared__ __align__(16) unsigned short aLds[128 * 32];
  __shared__ __align__(16) unsigned short bLds[128 * 32];
  const int tid  = threadIdx.x;
  const int wave = tid >> 6;
  const int lane = tid & 63;
  const int m0 = blockIdx.y * 128;
  const int n0 = blockIdx.x * 128;
  const int wr = wave >> 1;  // wave row (0..1) -> 64-row band
  const int wc = wave & 1;   // wave col (0..1) -> 64-col band

  f32x4 acc[4][4];
#pragma unroll
  for (int i = 0; i < 4; ++i)
#pragma unroll
    for (int j = 0; j < 4; ++j)
#pragma unroll
      for (int r = 0; r < 4; ++r) acc[i][j][r] = 0.f;

  const int srow = lane >> 2;        // 0..15 within a 16-row staging group
  const int kcol = (lane & 3) * 8;   // 0,8,16,24

  for (int k0 = 0; k0 < H; k0 += 32) {
#pragma unroll
    for (int p = 0; p < 2; ++p) {
      const int g = p * 4 + wave;  // staging group 0..7 (16 rows each)
      const unsigned short* ga = xb + (size_t)(m0 + g * 16 + srow) * H + k0 + kcol;
      const unsigned short* gb = wb + (size_t)(n0 + g * 16 + srow) * H + k0 + kcol;
      __builtin_amdgcn_global_load_lds(
          (const __attribute__((address_space(1))) unsigned int*)ga,
          (__attribute__((address_space(3))) unsigned int*)(aLds + g * 16 * 32), 16, 0, 0);
      __builtin_amdgcn_global_load_lds(
          (const __attribute__((address_space(1))) unsigned int*)gb,
          (__attribute__((address_space(3))) unsigned int*)(bLds + g * 16 * 32), 16, 0, 0);
    }
    __syncthreads();

    const int kc = (lane >> 4) * 8;   // k-chunk within 32
    const int ar = wr * 64 + (lane & 15);
    const int br = wc * 64 + (lane & 15);
    bf16x8 af[4], bfr[4];
#pragma unroll
    for (int i = 0; i < 4; ++i)
      af[i] = *reinterpret_cast<const bf16x8*>(aLds + (ar + i * 16) * 32 + kc);
#pragma unroll
    for (int j = 0; j < 4; ++j)
      bfr[j] = *reinterpret_cast<const bf16x8*>(bLds + (br + j * 16) * 32 + kc);
#pragma unroll
    for (int i = 0; i < 4; ++i)
#pragma unroll
      for (int j = 0; j < 4; ++j)
        acc[i][j] = __builtin_amdgcn_mfma_f32_16x16x32_bf16(af[i], bfr[j], acc[i][j], 0, 0, 0);
    __syncthreads();
  }

  const int cr = (lane >> 4) * 4;
  const int cc = lane & 15;
#pragma unroll
  for (int i = 0; i < 4; ++i)
#pragma unroll
    for (int j = 0; j < 4; ++j)
#pragma unroll
      for (int r = 0; r < 4; ++r)
        out[(size_t)(m0 + wr * 64 + i * 16 + cr + r) * H + (n0 + wc * 64 + j * 16 + cc)] =
            acc[i][j][r];
}

// ---------------- gate (fp32, exact top-2) + sparse contrib, out += ----------------
__global__ __launch_bounds__(256) void contrib_kernel(
    const float* __restrict__ x, const float* __restrict__ gate_w,
    const float* __restrict__ weighted, const int* __restrict__ mask_idx,
    float* __restrict__ out) {
  __shared__ float xrow[H];
  __shared__ float acc[H];
  __shared__ float lg[NEXP];
  __shared__ float wred[4][NEXP];
  const int t = blockIdx.x;
  const int tid = threadIdx.x;

  const float4* xr4 = reinterpret_cast<const float4*>(x + (size_t)t * H);
  for (int i = tid; i < H / 4; i += 256) {
    reinterpret_cast<float4*>(xrow)[i] = xr4[i];
    float4 z; z.x = 0.f; z.y = 0.f; z.z = 0.f; z.w = 0.f;
    reinterpret_cast<float4*>(acc)[i] = z;
  }
  __syncthreads();

  // gate logits: 8 dot products of length H
  float part[NEXP];
#pragma unroll
  for (int e = 0; e < NEXP; ++e) part[e] = 0.f;
  for (int j = tid; j < H; j += 256) {
    float xv = xrow[j];
#pragma unroll
    for (int e = 0; e < NEXP; ++e) part[e] = fmaf(xv, gate_w[e * H + j], part[e]);
  }
#pragma unroll
  for (int e = 0; e < NEXP; ++e) {
    float v = part[e];
    for (int off = 32; off > 0; off >>= 1) v += __shfl_down(v, off);
    part[e] = v;
  }
  const int wv = tid >> 6;
  const int lane = tid & 63;
  if (lane == 0) {
#pragma unroll
    for (int e = 0; e < NEXP; ++e) wred[wv][e] = part[e];
  }
  __syncthreads();
  if (tid < NEXP) {
    float s = wred[0][tid] + wred[1][tid] + wred[2][tid] + wred[3][tid];
    lg[tid] = fminf(fmaxf(s, -50.f), 50.f);
  }
  __syncthreads();

  // top-2 (redundant per thread; ties -> lower index, matches jax top_k)
  int e0 = 0; float w0 = lg[0];
#pragma unroll
  for (int e = 1; e < NEXP; ++e) { float v = lg[e]; if (v > w0) { w0 = v; e0 = e; } }
  int e1 = -1; float w1 = -3.4e38f;
#pragma unroll
  for (int e = 0; e < NEXP; ++e) {
    if (e == e0) continue;
    float v = lg[e];
    if (v > w1) { w1 = v; e1 = e; }
  }
  const float r1 = expf(w1 - w0);      // <= 1
  const float rw0 = 1.f / (1.f + r1);
  const float rw1 = r1 / (1.f + r1);

  const float* w0p = weighted + (size_t)e0 * NS;
  const float* w1p = weighted + (size_t)e1 * NS;
  for (int s = tid; s < NS; s += 256) {
    int m = mask_idx[s];
    int r = m >> LOGH;
    int c = m & (H - 1);
    float v = fmaf(rw0, w0p[s], rw1 * w1p[s]);
    atomicAdd(&acc[r], xrow[c] * v);
  }
  __syncthreads();

  float* orow = out + (size_t)t * H;
  for (int i = tid; i < H; i += 256) orow[i] += acc[i];
}

extern "C" void kernel_launch(void* const* d_in, const int* in_sizes, int n_in,
                              void* d_out, int out_size, void* d_ws, size_t ws_size,
                              hipStream_t stream) {
  const float* x          = (const float*)d_in[0];
  const float* gate_w     = (const float*)d_in[1];
  const float* W          = (const float*)d_in[2];
  const float* atoms      = (const float*)d_in[3];
  const float* eaw        = (const float*)d_in[4];
  const float* importance = (const float*)d_in[5];
  const int*   mask_idx   = (const int*)d_in[6];
  float* out = (float*)d_out;

  char* ws = (char*)d_ws;
  unsigned short* xb = (unsigned short*)ws;                               // T*H bf16 = 16 MB
  unsigned short* wb = (unsigned short*)(ws + (size_t)T_TOK * H * 2);     // H*H bf16 = 8 MB
  float* weighted = (float*)(ws + (size_t)T_TOK * H * 2 + (size_t)H * H * 2);  // E*NS f32

  cvt_kernel<<<2048, 256, 0, stream>>>(x, W, xb, wb);
  weighted_kernel<<<64, 256, 0, stream>>>(eaw, atoms, importance, weighted);
  gemm_kernel<<<dim3(H / 128, T_TOK / 128), 256, 0, stream>>>(xb, wb, out);
  contrib_kernel<<<T_TOK, 256, 0, stream>>>(x, gate_w, weighted, mask_idx, out);
}